// Round 22
// baseline (163.417 us; speedup 1.0000x reference)
//
#include <hip/hip_runtime.h>
#include <hip/hip_bf16.h>
#include <stdint.h>

// RoPE self-attention, bf16-MFMA pipeline.
// B=2 L=2048 D=1024 H=16 DK=64. GEMM1 fuses bias+RoPE+pack (Q,K) and
// bias+transpose (V), LDS-vectorized epilogue. GEMMs: 2-slot prefetch,
// 8 waves of 32x64 per 128x128 tile (4 waves/SIMD), T2 XOR-swizzled LDS,
// 2-D XCD-chunked grid swizzle. Loops partially unrolled (#pragma unroll)
// so buffer parity + swizzled sub-tile offsets fold to compile-time
// immediates (R21: VALUBusy 3x the source-level op count -> per-iter
// address recompute suspected). Attention: 32x32x16 MFMA, in-register P
// via cvt_pk+permlane32_swap, split-KV (z=2) additive partials + merge,
// phase-split inner loop (4 waves/SIMD). Q pre-scaled by 0.125*log2(e).

typedef __attribute__((ext_vector_type(8)))  short bf16x8;   // MFMA A/B frag
typedef __attribute__((ext_vector_type(4)))  float f32x4;    // 16x16 C/D frag
typedef __attribute__((ext_vector_type(16))) float f32x16;   // 32x32 C/D frag
typedef __attribute__((ext_vector_type(4)))  short short4v;
typedef __attribute__((ext_vector_type(4)))  unsigned int u32x4;

#define DEV static __device__ __forceinline__

DEV short f2bf(float f) {            // RNE f32->bf16
  uint32_t u = __builtin_bit_cast(uint32_t, f);
  u += 0x7FFFu + ((u >> 16) & 1u);
  return (short)(u >> 16);
}
DEV float bf2f(short s) {
  return __builtin_bit_cast(float, ((uint32_t)(uint16_t)s) << 16);
}
DEV uint32_t pkbf(float a, float b) { // packed f32x2 -> bf16x2 (v_cvt_pk path)
  __hip_bfloat162 h = __float22bfloat162_rn(make_float2(a, b));
  uint32_t u;
  __builtin_memcpy(&u, &h, 4);
  return u;
}
// v_permlane32_swap_b32 vdst, vsrc: dst.upper <-> src.lower (verified R7)
DEV void pl32swap(uint32_t &dst, uint32_t &src) {
  asm volatile("v_permlane32_swap_b32 %0, %1" : "+v"(dst), "+v"(src));
}

#define AS1 __attribute__((address_space(1)))
#define AS3 __attribute__((address_space(3)))
#define GLOAD_LDS16(gp, lp) \
  __builtin_amdgcn_global_load_lds((const AS1 void*)(gp), (AS3 void*)(lp), 16, 0, 0)

// ------------------------------------- f32 -> bf16, all three tensors fused
// blocks [0,4096): x (1048576 f4) | [4096,7168): Wqkv (786432) | rest: Wout.
__global__ void k_cvt_all(const float* __restrict__ x, const float* __restrict__ wq,
                          const float* __restrict__ wo,
                          short* __restrict__ xb, short* __restrict__ wqb,
                          short* __restrict__ wob) {
  int bid = blockIdx.x;
  const float* in;
  short* out;
  int i;
  if (bid < 4096)      { in = x;  out = xb;  i = bid * 256 + threadIdx.x; }
  else if (bid < 7168) { in = wq; out = wqb; i = (bid - 4096) * 256 + threadIdx.x; }
  else                 { in = wo; out = wob; i = (bid - 7168) * 256 + threadIdx.x; }
  float4 v = reinterpret_cast<const float4*>(in)[i];
  short4v o = { f2bf(v.x), f2bf(v.y), f2bf(v.z), f2bf(v.w) };
  reinterpret_cast<short4v*>(out)[i] = o;
}

// ---------------------------------------------- GEMM tile stage (128x64 x2)
// 512 threads: 2 chunks each of A and B. Source pre-swizzled (rule #21).
DEV void gemm_stage(const short* Ag, const short* Bg, int K_,
                    short* AsD, short* BsD, int tid) {
  #pragma unroll
  for (int p = 0; p < 2; ++p) {
    int f = p * 512 + tid;
    int row = f >> 3;
    int sch = (f & 7) ^ (row & 7);
    GLOAD_LDS16(Ag + (size_t)row * K_ + sch * 8, AsD + f * 8);
    GLOAD_LDS16(Bg + (size_t)row * K_ + sch * 8, BsD + f * 8);
  }
}

// -------------------------------------------------------------- GEMM template
// C128x128 = A[M][K] @ Bt[N][K]^T, BK=64, 8 waves (4 wr x 2 wc) of 32x64,
// 2-slot prefetch, T2 XOR swizzle. 2-D XCD chunking: XCD x owns an
// (gy/4 m) x (gx/2 n) tile rectangle, row-major inside. K-loop unrolled x2
// so gbuf parity is compile-time (addresses fold to immediates).
#define GEMM_BODY(A_, Bt_, K_)                                              \
  __shared__ short Lds[4 * 128 * 64];   /* 64KB: slot stride 16384 shorts */\
  const int tid = threadIdx.x;                                              \
  const int lane = tid & 63;                                                \
  const int wid  = tid >> 6;           /* 0..7 */                           \
  const int lq = lane & 15, lg = lane >> 4;                                 \
  const int wr = wid >> 1, wc = wid & 1;                                    \
  int lin_ = blockIdx.y * gridDim.x + blockIdx.x;                           \
  const int xcd_ = lin_ & 7;                                                \
  const int j_   = lin_ >> 3;                                               \
  const int hx_  = gridDim.x >> 1;     /* n tiles per chunk */              \
  const int hy_  = gridDim.y >> 2;     /* m tiles per chunk */              \
  const int m0 = ((xcd_ & 3) * hy_ + j_ / hx_) * 128;                       \
  const int n0 = ((xcd_ >> 2) * hx_ + j_ % hx_) * 128;                      \
  f32x4 acc[2][4];                                                          \
  _Pragma("unroll")                                                         \
  for (int i = 0; i < 2; ++i)                                               \
    _Pragma("unroll")                                                       \
    for (int j = 0; j < 4; ++j) acc[i][j] = (f32x4){0.f, 0.f, 0.f, 0.f};    \
  const int KT = (K_) >> 6;                                                 \
  gemm_stage((A_) + (size_t)m0 * (K_), (Bt_) + (size_t)n0 * (K_), (K_),     \
             Lds, Lds + 8192, tid);                                         \
  __syncthreads();                                                          \
  int gbuf = 0;                                                             \
  _Pragma("unroll 2")                                                       \
  for (int kt = 0; kt < KT; ++kt) {                                         \
    if (kt + 1 < KT)                                                        \
      gemm_stage((A_)  + (size_t)m0 * (K_) + (kt + 1) * 64,                 \
                 (Bt_) + (size_t)n0 * (K_) + (kt + 1) * 64, (K_),           \
                 Lds + (gbuf ^ 1) * 16384,                                  \
                 Lds + (gbuf ^ 1) * 16384 + 8192, tid);                     \
    const short* As = Lds + gbuf * 16384;                                   \
    const short* Bs = As + 8192;                                            \
    _Pragma("unroll")                                                       \
    for (int kk = 0; kk < 2; ++kk) {                                        \
      bf16x8 af[2], bfr[4];                                                 \
      _Pragma("unroll")                                                     \
      for (int i = 0; i < 2; ++i)                                           \
        af[i]  = *reinterpret_cast<const bf16x8*>(                          \
            &As[(wr*32 + i*16 + lq) * 64 + (((kk*4 + lg) ^ (lq & 7)) * 8)]);\
      _Pragma("unroll")                                                     \
      for (int j = 0; j < 4; ++j)                                           \
        bfr[j] = *reinterpret_cast<const bf16x8*>(                          \
            &Bs[(wc*64 + j*16 + lq) * 64 + (((kk*4 + lg) ^ (lq & 7)) * 8)]);\
      _Pragma("unroll")                                                     \
      for (int i = 0; i < 2; ++i)                                           \
        _Pragma("unroll")                                                   \
        for (int j = 0; j < 4; ++j)                                         \
          acc[i][j] = __builtin_amdgcn_mfma_f32_16x16x32_bf16(              \
              af[i], bfr[j], acc[i][j], 0, 0, 0);                           \
    }                                                                       \
    __syncthreads();                                                        \
    gbuf ^= 1;                                                              \
  }

// ---------------- GEMM1: x @ Wqkv^T + b, fused RoPE(Q,K-scaled) + V-transpose
__global__ __launch_bounds__(512, 4) void k_gemm_qkv(
    const short* __restrict__ A, const short* __restrict__ Bt,
    const float* __restrict__ bias,
    const float* __restrict__ cosb, const float* __restrict__ sinb,
    short* __restrict__ Qb, short* __restrict__ Kb, short* __restrict__ Vt)
{
  GEMM_BODY(A, Bt, 1024)

  short* Ep = Lds + wid * 2048;                // per-wave 4KB scratch
  const int cglob = n0 + wc * 64;              // head base col in [0,3072)
  if (cglob < 2048) {                          // ---- Q or K: bias + RoPE
    const bool isq = (cglob < 1024);
    const float QS = isq ? 0.125f * 1.4426950408889634f : 1.0f;
    short* dst = isq ? Qb : Kb;
    const int h = (cglob & 1023) >> 6;
    const float b0 = bias[cglob + lq],      b2 = bias[cglob + 32 + lq];
    const float b1 = bias[cglob + 16 + lq], b3 = bias[cglob + 48 + lq];
    #pragma unroll
    for (int i = 0; i < 2; ++i) {
      #pragma unroll
      for (int r = 0; r < 4; ++r) {
        int lloc = i*16 + lg*4 + r;                // 0..31 within wave strip
        int rg = m0 + wr*32 + lloc;                // global row = b*2048 + l
        float c0 = cosb[(size_t)rg * 32 + lq];
        float s0 = sinb[(size_t)rg * 32 + lq];
        float c1 = cosb[(size_t)rg * 32 + 16 + lq];
        float s1 = sinb[(size_t)rg * 32 + 16 + lq];
        float x1 = acc[i][0][r] + b0, x2 = acc[i][2][r] + b2;   // d = lq
        Ep[lloc*64 + lq]      = f2bf((x1 * c0 - x2 * s0) * QS);
        Ep[lloc*64 + 32 + lq] = f2bf((x1 * s0 + x2 * c0) * QS);
        float y1 = acc[i][1][r] + b1, y2 = acc[i][3][r] + b3;   // d = 16+lq
        Ep[lloc*64 + 16 + lq] = f2bf((y1 * c1 - y2 * s1) * QS);
        Ep[lloc*64 + 48 + lq] = f2bf((y1 * s1 + y2 * c1) * QS);
      }
    }
    #pragma unroll
    for (int p = 0; p < 4; ++p) {              // 256 chunks / 64 lanes
      int f = p * 64 + lane;
      int lloc = f >> 3, d0 = (f & 7) * 8;
      int rg = m0 + wr*32 + lloc;
      int bi = rg >> 11, ll = rg & 2047;
      bf16x8 v = *reinterpret_cast<const bf16x8*>(&Ep[lloc*64 + d0]);
      *reinterpret_cast<bf16x8*>(
          &dst[((size_t)(bi * 16 + h) * 2048 + ll) * 64 + d0]) = v;
    }
  } else {                                     // ---- V: bias + transpose
    const int h = (cglob - 2048) >> 6;
    // d-major Ep[d][32 l], swizzle lloc ^= ((d>>1)&3)<<3 (8 16B slots/16
    // lanes = 2-way = free; 16B read-back stays contiguous)
    #pragma unroll
    for (int i = 0; i < 2; ++i) {
      int lloc = i*16 + lg*4;                      // 4 consecutive l
      #pragma unroll
      for (int j = 0; j < 4; ++j) {
        int d = j * 16 + lq;
        float bv = bias[cglob + d];
        short4v pk4 = { f2bf(acc[i][j][0] + bv), f2bf(acc[i][j][1] + bv),
                        f2bf(acc[i][j][2] + bv), f2bf(acc[i][j][3] + bv) };
        *reinterpret_cast<short4v*>(
            &Ep[d*32 + (lloc ^ (((d >> 1) & 3) << 3))]) = pk4;
      }
    }
    #pragma unroll
    for (int p = 0; p < 4; ++p) {              // 256 chunks: 64 d x 4 of 8l
      int f = p * 64 + lane;
      int d = f >> 2, lc = (f & 3) * 8;
      bf16x8 v = *reinterpret_cast<const bf16x8*>(&Ep[d*32 + lc]);
      int lreal = lc ^ (((d >> 1) & 3) << 3);
      int rg = m0 + wr*32 + lreal;                 // 8-aligned run of l
      int bi = rg >> 11, ll = rg & 2047;
      *reinterpret_cast<bf16x8*>(
          &Vt[((size_t)(bi * 16 + h) * 64 + d) * 2048 + ll]) = v;
    }
  }
}

// -------------------------------------------- GEMM2: AO @ Wout^T + b, f32 out
__global__ __launch_bounds__(512, 4) void k_gemm_out(
    const short* __restrict__ A, const short* __restrict__ Bt,
    const float* __restrict__ bias, float* __restrict__ C)
{
  GEMM_BODY(A, Bt, 1024)
  const int N = 1024;
  #pragma unroll
  for (int i = 0; i < 2; ++i) {
    int rbase = m0 + wr*32 + i*16 + lg*4;
    #pragma unroll
    for (int j = 0; j < 4; ++j) {
      int col = n0 + wc*64 + j*16 + lq;
      float bv = bias[col];
      #pragma unroll
      for (int r = 0; r < 4; ++r)
        C[(size_t)(rbase + r) * N + col] = acc[i][j][r] + bv;
    }
  }
}

// ------------------------------------------------------------ flash attention
// Split-KV: blockIdx.z selects kv-half (16 tiles of 64). 4 waves/block,
// 32 q-rows/wave (32x32x16 MFMA). K/V staged in LDS, 2-buffer. Phase-split
// inner loop keeps unified VGPR+AGPR < 128 -> 4 waves/SIMD. kv-loop
// unrolled x4: cur parity + swizzled sub-tile offsets fold to immediates.
__global__ __launch_bounds__(256, 4) void k_attn(
    const short* __restrict__ Q, const short* __restrict__ Kb,
    const short* __restrict__ Vt,
    short* __restrict__ P0, short* __restrict__ P1,
    float* __restrict__ L0, float* __restrict__ L1)
{
  __shared__ short Ks[2][64 * 64];   // 8KB x2, swizzled, rows = kv
  __shared__ short Vs[2][64 * 64];   // 8KB x2, swizzled, rows = d
  const int tid = threadIdx.x;
  const int lane = tid & 63;
  const int wid  = tid >> 6;         // 0..3
  const int Lq = lane & 31;          // q-col / d-col / kv-row
  const int h  = lane >> 5;          // half-select
  const int bh = blockIdx.y;
  const int q0 = blockIdx.x * 128 + wid * 32;
  const int b = bh >> 4, hh = bh & 15;
  const int t0 = blockIdx.z * 16;    // kv-tile base for this half
  short* Pp = blockIdx.z ? P1 : P0;
  float* Lp = blockIdx.z ? L1 : L0;

  const short* Qp = Q  + ((size_t)bh * 2048 + q0 + Lq) * 64;
  const short* Kp = Kb + (size_t)bh * 2048 * 64;
  const short* Vp = Vt + (size_t)bh * 64 * 2048;

  #define STAGE_KV(c, t) do {                                              \
    const short* Kg_ = Kp + (size_t)(t) * 64 * 64;                         \
    const short* Vg_ = Vp + (size_t)(t) * 64;                              \
    _Pragma("unroll")                                                      \
    for (int p_ = 0; p_ < 2; ++p_) {                                       \
      int f_ = p_ * 256 + tid;                                             \
      int row_ = f_ >> 3;                                                  \
      int sch_ = (f_ & 7) ^ (row_ & 7);                                    \
      GLOAD_LDS16(Kg_ + row_ * 64 + sch_ * 8,            &Ks[c][f_ * 8]);  \
      GLOAD_LDS16(Vg_ + (size_t)row_ * 2048 + sch_ * 8,  &Vs[c][f_ * 8]);  \
    }                                                                      \
  } while (0)

  bf16x8 qf[4];
  #pragma unroll
  for (int ks = 0; ks < 4; ++ks)
    qf[ks] = *reinterpret_cast<const bf16x8*>(Qp + ks * 16 + h * 8);

  f32x16 o[2];
  #pragma unroll
  for (int nd = 0; nd < 2; ++nd)
    #pragma unroll
    for (int r = 0; r < 16; ++r) o[nd][r] = 0.f;
  float la0 = 0.f, la1 = 0.f;

  STAGE_KV(0, t0);
  asm volatile("s_waitcnt vmcnt(0)" ::: "memory");
  __syncthreads();

  #pragma unroll 4
  for (int kk2 = 0; kk2 < 16; ++kk2) {
    const int cur = kk2 & 1;
    if (kk2 < 15) STAGE_KV(cur ^ 1, t0 + kk2 + 1);   // prefetch overlaps

    #pragma unroll
    for (int mb = 0; mb < 2; ++mb) {       // 32-kv half of the tile
      f32x16 sm;
      #pragma unroll
      for (int r = 0; r < 16; ++r) sm[r] = 0.f;
      #pragma unroll
      for (int ks = 0; ks < 4; ++ks) {
        bf16x8 kf = *reinterpret_cast<const bf16x8*>(
            &Ks[cur][(mb*32 + Lq) * 64 + (((ks*2 + h) ^ (Lq & 7)) * 8)]);
        sm = __builtin_amdgcn_mfma_f32_32x32x16_bf16(kf, qf[ks], sm, 0, 0, 0);
      }
      #pragma unroll
      for (int half = 0; half < 2; ++half) {
        float e0 = __builtin_amdgcn_exp2f(sm[8*half + 0]);
        float e1 = __builtin_amdgcn_exp2f(sm[8*half + 1]);
        float e2 = __builtin_amdgcn_exp2f(sm[8*half + 2]);
        float e3 = __builtin_amdgcn_exp2f(sm[8*half + 3]);
        float e4 = __builtin_amdgcn_exp2f(sm[8*half + 4]);
        float e5 = __builtin_amdgcn_exp2f(sm[8*half + 5]);
        float e6 = __builtin_amdgcn_exp2f(sm[8*half + 6]);
        float e7 = __builtin_amdgcn_exp2f(sm[8*half + 7]);
        la0 += (e0 + e1) + (e4 + e5);
        la1 += (e2 + e3) + (e6 + e7);
        uint32_t w0 = pkbf(e0, e1), w1 = pkbf(e2, e3);
        uint32_t w2 = pkbf(e4, e5), w3 = pkbf(e6, e7);
        pl32swap(w0, w2);
        pl32swap(w1, w3);
        u32x4 paw = { w0, w1, w2, w3 };
        bf16x8 pa = __builtin_bit_cast(bf16x8, paw);
        const int ksl = mb * 2 + half;     // kv-slot 0..3
        #pragma unroll
        for (int nd = 0; nd < 2; ++nd) {
          bf16x8 vf = *reinterpret_cast<const bf16x8*>(
              &Vs[cur][(nd*32 + Lq) * 64 + (((ksl*2 + h) ^ (Lq & 7)) * 8)]);
          o[nd] = __builtin_amdgcn_mfma_f32_32x32x16_bf16(pa, vf, o[nd], 0, 0, 0);
        }
      }
    }
    asm volatile("s_waitcnt vmcnt(0)" ::: "memory");
    __syncthreads();                 // next tile staged; buffers swap
  }

  // ---- epilogue: partial l + UNNORMALIZED o (merge kernel normalizes)
  float l_part = la0 + la1;
  l_part += __shfl_xor(l_part, 32, 64);      // both h now hold full partial l
  if (h == 0) Lp[((size_t)bh << 11) + q0 + Lq] = l_part;
  #pragma unroll
  for (int r = 0; r < 16; ++r) {
    int qrow = (r & 3) + 8 * (r >> 2) + 4 * h;
    size_t rowb = ((size_t)b * 2048 + q0 + qrow) * 1024 + hh * 64;
    Pp[rowb + Lq]      = f2bf(o[0][r]);
    Pp[rowb + 32 + Lq] = f2bf(o[1][r]);
  }
  #undef STAGE_KV
}

// ------------------------------------- merge: AO = (P0+P1) / (l0+l1), bf16
__global__ void k_merge(const short* __restrict__ P0, const short* __restrict__ P1,
                        const float* __restrict__ L0, const float* __restrict__ L1,
                        short* __restrict__ AO)
{
  int idx = blockIdx.x * 256 + threadIdx.x;   // 8 elems each; 524288 threads
  int rg = idx >> 7;                 // row 0..4095 = b*2048 + l
  int c0 = (idx & 127) * 8;          // col base (within one 64-col head)
  int bh = ((rg >> 11) << 4) + (c0 >> 6);
  size_t lix = ((size_t)bh << 11) + (rg & 2047);
  float inv = 1.f / (L0[lix] + L1[lix]);
  size_t off = (size_t)rg * 1024 + c0;
  bf16x8 a = *reinterpret_cast<const bf16x8*>(&P0[off]);
  bf16x8 bv = *reinterpret_cast<const bf16x8*>(&P1[off]);
  bf16x8 r;
  #pragma unroll
  for (int j = 0; j < 8; ++j)
    r[j] = f2bf((bf2f(a[j]) + bf2f(bv[j])) * inv);
  *reinterpret_cast<bf16x8*>(&AO[off]) = r;
}

// ----------------------------------------------------------------------------
extern "C" void kernel_launch(void* const* d_in, const int* in_sizes, int n_in,
                              void* d_out, int out_size, void* d_ws, size_t ws_size,
                              hipStream_t stream) {
  (void)in_sizes; (void)n_in; (void)out_size; (void)ws_size;
  const float* x    = (const float*)d_in[0];
  const float* rc   = (const float*)d_in[1];
  const float* rs   = (const float*)d_in[2];
  const float* Wqkv = (const float*)d_in[3];
  const float* bqkv = (const float*)d_in[4];
  const float* Wout = (const float*)d_in[5];
  const float* bout = (const float*)d_in[6];
  float* out = (float*)d_out;

  char* ws = (char*)d_ws;
  short* xb  = (short*)(ws);              // x bf16        [4096][1024]  8.39MB
  short* wqb = (short*)(ws + 8388608);    // Wqkv bf16     [3072][1024]  6.29MB
  short* wob = (short*)(ws + 14680064);   // Wout bf16     [1024][1024]  2.10MB
  short* Qb  = (short*)(ws + 16777216);   // Q roped+scaled[32][2048][64] 8.39MB
  short* Kb  = (short*)(ws + 25165824);   // K roped       [32][2048][64] 8.39MB
  short* Vt  = (short*)(ws + 33554432);   // V transposed  [32][64][2048] 8.39MB
  short* P0  = (short*)(ws + 41943040);   // o partial z=0 [4096][1024]  8.39MB
  short* P1  = (short*)(ws + 50331648);   // o partial z=1 [4096][1024]  8.39MB
  float* L0  = (float*)(ws + 58720256);   // l partial z=0 [32][2048]    0.26MB
  float* L1  = (float*)(ws + 58982400);   // l partial z=1 [32][2048]    0.26MB
                                          // total 59.2MB

  k_cvt_all<<<8192, 256, 0, stream>>>(x, Wqkv, Wout, xb, wqb, wob);
  k_gemm_qkv<<<dim3(24, 32), 512, 0, stream>>>(xb, wqb, bqkv, rc, rs, Qb, Kb, Vt);
  k_attn<<<dim3(16, 32, 2), 256, 0, stream>>>(Qb, Kb, Vt, P0, P1, L0, L1);
  k_merge<<<2048, 256, 0, stream>>>(P0, P1, L0, L1, P0);
  k_gemm_out<<<dim3(8, 32), 512, 0, stream>>>(P0, wob, bout, out);
}

// Round 23
// 111.188 us; speedup vs baseline: 1.4697x; 1.4697x over previous
//
#include <hip/hip_runtime.h>
#include <hip/hip_bf16.h>
#include <stdint.h>

// RoPE self-attention, bf16-MFMA pipeline.
// B=2 L=2048 D=1024 H=16 DK=64. GEMM1 fuses bias+RoPE+pack (Q,K) and
// bias+transpose (V), LDS-vectorized epilogue. GEMMs: 2-slot prefetch,
// 8 waves of 32x64 per 128x128 tile (4 waves/SIMD), T2 XOR-swizzled LDS,
// 2-D XCD-chunked grid swizzle, K-loop unroll x2 (parity folds).
// Attention: NO unroll on the kv loop (R22: unroll 4 spilled the f32x16
// accumulators to scratch under launch_bounds(256,4) -- 225MB scratch
// writes, 2.2x slowdown). 32x32x16 MFMA, in-register P via
// cvt_pk+permlane32_swap, split-KV (z=2) additive partials + merge,
// phase-split inner loop (4 waves/SIMD). Q pre-scaled by 0.125*log2(e).

typedef __attribute__((ext_vector_type(8)))  short bf16x8;   // MFMA A/B frag
typedef __attribute__((ext_vector_type(4)))  float f32x4;    // 16x16 C/D frag
typedef __attribute__((ext_vector_type(16))) float f32x16;   // 32x32 C/D frag
typedef __attribute__((ext_vector_type(4)))  short short4v;
typedef __attribute__((ext_vector_type(4)))  unsigned int u32x4;

#define DEV static __device__ __forceinline__

DEV short f2bf(float f) {            // RNE f32->bf16
  uint32_t u = __builtin_bit_cast(uint32_t, f);
  u += 0x7FFFu + ((u >> 16) & 1u);
  return (short)(u >> 16);
}
DEV float bf2f(short s) {
  return __builtin_bit_cast(float, ((uint32_t)(uint16_t)s) << 16);
}
DEV uint32_t pkbf(float a, float b) { // packed f32x2 -> bf16x2 (v_cvt_pk path)
  __hip_bfloat162 h = __float22bfloat162_rn(make_float2(a, b));
  uint32_t u;
  __builtin_memcpy(&u, &h, 4);
  return u;
}
// v_permlane32_swap_b32 vdst, vsrc: dst.upper <-> src.lower (verified R7)
DEV void pl32swap(uint32_t &dst, uint32_t &src) {
  asm volatile("v_permlane32_swap_b32 %0, %1" : "+v"(dst), "+v"(src));
}

#define AS1 __attribute__((address_space(1)))
#define AS3 __attribute__((address_space(3)))
#define GLOAD_LDS16(gp, lp) \
  __builtin_amdgcn_global_load_lds((const AS1 void*)(gp), (AS3 void*)(lp), 16, 0, 0)

// ------------------------------------- f32 -> bf16, all three tensors fused
// blocks [0,4096): x (1048576 f4) | [4096,7168): Wqkv (786432) | rest: Wout.
__global__ void k_cvt_all(const float* __restrict__ x, const float* __restrict__ wq,
                          const float* __restrict__ wo,
                          short* __restrict__ xb, short* __restrict__ wqb,
                          short* __restrict__ wob) {
  int bid = blockIdx.x;
  const float* in;
  short* out;
  int i;
  if (bid < 4096)      { in = x;  out = xb;  i = bid * 256 + threadIdx.x; }
  else if (bid < 7168) { in = wq; out = wqb; i = (bid - 4096) * 256 + threadIdx.x; }
  else                 { in = wo; out = wob; i = (bid - 7168) * 256 + threadIdx.x; }
  float4 v = reinterpret_cast<const float4*>(in)[i];
  short4v o = { f2bf(v.x), f2bf(v.y), f2bf(v.z), f2bf(v.w) };
  reinterpret_cast<short4v*>(out)[i] = o;
}

// ---------------------------------------------- GEMM tile stage (128x64 x2)
// 512 threads: 2 chunks each of A and B. Source pre-swizzled (rule #21).
DEV void gemm_stage(const short* Ag, const short* Bg, int K_,
                    short* AsD, short* BsD, int tid) {
  #pragma unroll
  for (int p = 0; p < 2; ++p) {
    int f = p * 512 + tid;
    int row = f >> 3;
    int sch = (f & 7) ^ (row & 7);
    GLOAD_LDS16(Ag + (size_t)row * K_ + sch * 8, AsD + f * 8);
    GLOAD_LDS16(Bg + (size_t)row * K_ + sch * 8, BsD + f * 8);
  }
}

// -------------------------------------------------------------- GEMM template
// C128x128 = A[M][K] @ Bt[N][K]^T, BK=64, 8 waves (4 wr x 2 wc) of 32x64,
// 2-slot prefetch, T2 XOR swizzle. 2-D XCD chunking: XCD x owns an
// (gy/4 m) x (gx/2 n) tile rectangle, row-major inside. K-loop unrolled x2
// so gbuf parity is compile-time (addresses fold to immediates).
#define GEMM_BODY(A_, Bt_, K_)                                              \
  __shared__ short Lds[4 * 128 * 64];   /* 64KB: slot stride 16384 shorts */\
  const int tid = threadIdx.x;                                              \
  const int lane = tid & 63;                                                \
  const int wid  = tid >> 6;           /* 0..7 */                           \
  const int lq = lane & 15, lg = lane >> 4;                                 \
  const int wr = wid >> 1, wc = wid & 1;                                    \
  int lin_ = blockIdx.y * gridDim.x + blockIdx.x;                           \
  const int xcd_ = lin_ & 7;                                                \
  const int j_   = lin_ >> 3;                                               \
  const int hx_  = gridDim.x >> 1;     /* n tiles per chunk */              \
  const int hy_  = gridDim.y >> 2;     /* m tiles per chunk */              \
  const int m0 = ((xcd_ & 3) * hy_ + j_ / hx_) * 128;                       \
  const int n0 = ((xcd_ >> 2) * hx_ + j_ % hx_) * 128;                      \
  f32x4 acc[2][4];                                                          \
  _Pragma("unroll")                                                         \
  for (int i = 0; i < 2; ++i)                                               \
    _Pragma("unroll")                                                       \
    for (int j = 0; j < 4; ++j) acc[i][j] = (f32x4){0.f, 0.f, 0.f, 0.f};    \
  const int KT = (K_) >> 6;                                                 \
  gemm_stage((A_) + (size_t)m0 * (K_), (Bt_) + (size_t)n0 * (K_), (K_),     \
             Lds, Lds + 8192, tid);                                         \
  __syncthreads();                                                          \
  int gbuf = 0;                                                             \
  _Pragma("unroll 2")                                                       \
  for (int kt = 0; kt < KT; ++kt) {                                         \
    if (kt + 1 < KT)                                                        \
      gemm_stage((A_)  + (size_t)m0 * (K_) + (kt + 1) * 64,                 \
                 (Bt_) + (size_t)n0 * (K_) + (kt + 1) * 64, (K_),           \
                 Lds + (gbuf ^ 1) * 16384,                                  \
                 Lds + (gbuf ^ 1) * 16384 + 8192, tid);                     \
    const short* As = Lds + gbuf * 16384;                                   \
    const short* Bs = As + 8192;                                            \
    _Pragma("unroll")                                                       \
    for (int kk = 0; kk < 2; ++kk) {                                        \
      bf16x8 af[2], bfr[4];                                                 \
      _Pragma("unroll")                                                     \
      for (int i = 0; i < 2; ++i)                                           \
        af[i]  = *reinterpret_cast<const bf16x8*>(                          \
            &As[(wr*32 + i*16 + lq) * 64 + (((kk*4 + lg) ^ (lq & 7)) * 8)]);\
      _Pragma("unroll")                                                     \
      for (int j = 0; j < 4; ++j)                                           \
        bfr[j] = *reinterpret_cast<const bf16x8*>(                          \
            &Bs[(wc*64 + j*16 + lq) * 64 + (((kk*4 + lg) ^ (lq & 7)) * 8)]);\
      _Pragma("unroll")                                                     \
      for (int i = 0; i < 2; ++i)                                           \
        _Pragma("unroll")                                                   \
        for (int j = 0; j < 4; ++j)                                         \
          acc[i][j] = __builtin_amdgcn_mfma_f32_16x16x32_bf16(              \
              af[i], bfr[j], acc[i][j], 0, 0, 0);                           \
    }                                                                       \
    __syncthreads();                                                        \
    gbuf ^= 1;                                                              \
  }

// ---------------- GEMM1: x @ Wqkv^T + b, fused RoPE(Q,K-scaled) + V-transpose
__global__ __launch_bounds__(512, 4) void k_gemm_qkv(
    const short* __restrict__ A, const short* __restrict__ Bt,
    const float* __restrict__ bias,
    const float* __restrict__ cosb, const float* __restrict__ sinb,
    short* __restrict__ Qb, short* __restrict__ Kb, short* __restrict__ Vt)
{
  GEMM_BODY(A, Bt, 1024)

  short* Ep = Lds + wid * 2048;                // per-wave 4KB scratch
  const int cglob = n0 + wc * 64;              // head base col in [0,3072)
  if (cglob < 2048) {                          // ---- Q or K: bias + RoPE
    const bool isq = (cglob < 1024);
    const float QS = isq ? 0.125f * 1.4426950408889634f : 1.0f;
    short* dst = isq ? Qb : Kb;
    const int h = (cglob & 1023) >> 6;
    const float b0 = bias[cglob + lq],      b2 = bias[cglob + 32 + lq];
    const float b1 = bias[cglob + 16 + lq], b3 = bias[cglob + 48 + lq];
    #pragma unroll
    for (int i = 0; i < 2; ++i) {
      #pragma unroll
      for (int r = 0; r < 4; ++r) {
        int lloc = i*16 + lg*4 + r;                // 0..31 within wave strip
        int rg = m0 + wr*32 + lloc;                // global row = b*2048 + l
        float c0 = cosb[(size_t)rg * 32 + lq];
        float s0 = sinb[(size_t)rg * 32 + lq];
        float c1 = cosb[(size_t)rg * 32 + 16 + lq];
        float s1 = sinb[(size_t)rg * 32 + 16 + lq];
        float x1 = acc[i][0][r] + b0, x2 = acc[i][2][r] + b2;   // d = lq
        Ep[lloc*64 + lq]      = f2bf((x1 * c0 - x2 * s0) * QS);
        Ep[lloc*64 + 32 + lq] = f2bf((x1 * s0 + x2 * c0) * QS);
        float y1 = acc[i][1][r] + b1, y2 = acc[i][3][r] + b3;   // d = 16+lq
        Ep[lloc*64 + 16 + lq] = f2bf((y1 * c1 - y2 * s1) * QS);
        Ep[lloc*64 + 48 + lq] = f2bf((y1 * s1 + y2 * c1) * QS);
      }
    }
    #pragma unroll
    for (int p = 0; p < 4; ++p) {              // 256 chunks / 64 lanes
      int f = p * 64 + lane;
      int lloc = f >> 3, d0 = (f & 7) * 8;
      int rg = m0 + wr*32 + lloc;
      int bi = rg >> 11, ll = rg & 2047;
      bf16x8 v = *reinterpret_cast<const bf16x8*>(&Ep[lloc*64 + d0]);
      *reinterpret_cast<bf16x8*>(
          &dst[((size_t)(bi * 16 + h) * 2048 + ll) * 64 + d0]) = v;
    }
  } else {                                     // ---- V: bias + transpose
    const int h = (cglob - 2048) >> 6;
    // d-major Ep[d][32 l], swizzle lloc ^= ((d>>1)&3)<<3 (8 16B slots/16
    // lanes = 2-way = free; 16B read-back stays contiguous)
    #pragma unroll
    for (int i = 0; i < 2; ++i) {
      int lloc = i*16 + lg*4;                      // 4 consecutive l
      #pragma unroll
      for (int j = 0; j < 4; ++j) {
        int d = j * 16 + lq;
        float bv = bias[cglob + d];
        short4v pk4 = { f2bf(acc[i][j][0] + bv), f2bf(acc[i][j][1] + bv),
                        f2bf(acc[i][j][2] + bv), f2bf(acc[i][j][3] + bv) };
        *reinterpret_cast<short4v*>(
            &Ep[d*32 + (lloc ^ (((d >> 1) & 3) << 3))]) = pk4;
      }
    }
    #pragma unroll
    for (int p = 0; p < 4; ++p) {              // 256 chunks: 64 d x 4 of 8l
      int f = p * 64 + lane;
      int d = f >> 2, lc = (f & 3) * 8;
      bf16x8 v = *reinterpret_cast<const bf16x8*>(&Ep[d*32 + lc]);
      int lreal = lc ^ (((d >> 1) & 3) << 3);
      int rg = m0 + wr*32 + lreal;                 // 8-aligned run of l
      int bi = rg >> 11, ll = rg & 2047;
      *reinterpret_cast<bf16x8*>(
          &Vt[((size_t)(bi * 16 + h) * 64 + d) * 2048 + ll]) = v;
    }
  }
}

// -------------------------------------------- GEMM2: AO @ Wout^T + b, f32 out
__global__ __launch_bounds__(512, 4) void k_gemm_out(
    const short* __restrict__ A, const short* __restrict__ Bt,
    const float* __restrict__ bias, float* __restrict__ C)
{
  GEMM_BODY(A, Bt, 1024)
  const int N = 1024;
  #pragma unroll
  for (int i = 0; i < 2; ++i) {
    int rbase = m0 + wr*32 + i*16 + lg*4;
    #pragma unroll
    for (int j = 0; j < 4; ++j) {
      int col = n0 + wc*64 + j*16 + lq;
      float bv = bias[col];
      #pragma unroll
      for (int r = 0; r < 4; ++r)
        C[(size_t)(rbase + r) * N + col] = acc[i][j][r] + bv;
    }
  }
}

// ------------------------------------------------------------ flash attention
// Split-KV: blockIdx.z selects kv-half (16 tiles of 64). 4 waves/block,
// 32 q-rows/wave (32x32x16 MFMA). K/V staged in LDS, 2-buffer. Phase-split
// inner loop keeps unified VGPR+AGPR < 128 -> 4 waves/SIMD. NO kv-loop
// unroll (R22: unroll spilled accumulators to scratch).
__global__ __launch_bounds__(256, 4) void k_attn(
    const short* __restrict__ Q, const short* __restrict__ Kb,
    const short* __restrict__ Vt,
    short* __restrict__ P0, short* __restrict__ P1,
    float* __restrict__ L0, float* __restrict__ L1)
{
  __shared__ short Ks[2][64 * 64];   // 8KB x2, swizzled, rows = kv
  __shared__ short Vs[2][64 * 64];   // 8KB x2, swizzled, rows = d
  const int tid = threadIdx.x;
  const int lane = tid & 63;
  const int wid  = tid >> 6;         // 0..3
  const int Lq = lane & 31;          // q-col / d-col / kv-row
  const int h  = lane >> 5;          // half-select
  const int bh = blockIdx.y;
  const int q0 = blockIdx.x * 128 + wid * 32;
  const int b = bh >> 4, hh = bh & 15;
  const int t0 = blockIdx.z * 16;    // kv-tile base for this half
  short* Pp = blockIdx.z ? P1 : P0;
  float* Lp = blockIdx.z ? L1 : L0;

  const short* Qp = Q  + ((size_t)bh * 2048 + q0 + Lq) * 64;
  const short* Kp = Kb + (size_t)bh * 2048 * 64;
  const short* Vp = Vt + (size_t)bh * 64 * 2048;

  #define STAGE_KV(c, t) do {                                              \
    const short* Kg_ = Kp + (size_t)(t) * 64 * 64;                         \
    const short* Vg_ = Vp + (size_t)(t) * 64;                              \
    _Pragma("unroll")                                                      \
    for (int p_ = 0; p_ < 2; ++p_) {                                       \
      int f_ = p_ * 256 + tid;                                             \
      int row_ = f_ >> 3;                                                  \
      int sch_ = (f_ & 7) ^ (row_ & 7);                                    \
      GLOAD_LDS16(Kg_ + row_ * 64 + sch_ * 8,            &Ks[c][f_ * 8]);  \
      GLOAD_LDS16(Vg_ + (size_t)row_ * 2048 + sch_ * 8,  &Vs[c][f_ * 8]);  \
    }                                                                      \
  } while (0)

  bf16x8 qf[4];
  #pragma unroll
  for (int ks = 0; ks < 4; ++ks)
    qf[ks] = *reinterpret_cast<const bf16x8*>(Qp + ks * 16 + h * 8);

  f32x16 o[2];
  #pragma unroll
  for (int nd = 0; nd < 2; ++nd)
    #pragma unroll
    for (int r = 0; r < 16; ++r) o[nd][r] = 0.f;
  float la0 = 0.f, la1 = 0.f;

  STAGE_KV(0, t0);
  asm volatile("s_waitcnt vmcnt(0)" ::: "memory");
  __syncthreads();

  for (int kk2 = 0; kk2 < 16; ++kk2) {
    const int cur = kk2 & 1;
    if (kk2 < 15) STAGE_KV(cur ^ 1, t0 + kk2 + 1);   // prefetch overlaps

    #pragma unroll
    for (int mb = 0; mb < 2; ++mb) {       // 32-kv half of the tile
      f32x16 sm;
      #pragma unroll
      for (int r = 0; r < 16; ++r) sm[r] = 0.f;
      #pragma unroll
      for (int ks = 0; ks < 4; ++ks) {
        bf16x8 kf = *reinterpret_cast<const bf16x8*>(
            &Ks[cur][(mb*32 + Lq) * 64 + (((ks*2 + h) ^ (Lq & 7)) * 8)]);
        sm = __builtin_amdgcn_mfma_f32_32x32x16_bf16(kf, qf[ks], sm, 0, 0, 0);
      }
      #pragma unroll
      for (int half = 0; half < 2; ++half) {
        float e0 = __builtin_amdgcn_exp2f(sm[8*half + 0]);
        float e1 = __builtin_amdgcn_exp2f(sm[8*half + 1]);
        float e2 = __builtin_amdgcn_exp2f(sm[8*half + 2]);
        float e3 = __builtin_amdgcn_exp2f(sm[8*half + 3]);
        float e4 = __builtin_amdgcn_exp2f(sm[8*half + 4]);
        float e5 = __builtin_amdgcn_exp2f(sm[8*half + 5]);
        float e6 = __builtin_amdgcn_exp2f(sm[8*half + 6]);
        float e7 = __builtin_amdgcn_exp2f(sm[8*half + 7]);
        la0 += (e0 + e1) + (e4 + e5);
        la1 += (e2 + e3) + (e6 + e7);
        uint32_t w0 = pkbf(e0, e1), w1 = pkbf(e2, e3);
        uint32_t w2 = pkbf(e4, e5), w3 = pkbf(e6, e7);
        pl32swap(w0, w2);
        pl32swap(w1, w3);
        u32x4 paw = { w0, w1, w2, w3 };
        bf16x8 pa = __builtin_bit_cast(bf16x8, paw);
        const int ksl = mb * 2 + half;     // kv-slot 0..3
        #pragma unroll
        for (int nd = 0; nd < 2; ++nd) {
          bf16x8 vf = *reinterpret_cast<const bf16x8*>(
              &Vs[cur][(nd*32 + Lq) * 64 + (((ksl*2 + h) ^ (Lq & 7)) * 8)]);
          o[nd] = __builtin_amdgcn_mfma_f32_32x32x16_bf16(pa, vf, o[nd], 0, 0, 0);
        }
      }
    }
    asm volatile("s_waitcnt vmcnt(0)" ::: "memory");
    __syncthreads();                 // next tile staged; buffers swap
  }

  // ---- epilogue: partial l + UNNORMALIZED o (merge kernel normalizes)
  float l_part = la0 + la1;
  l_part += __shfl_xor(l_part, 32, 64);      // both h now hold full partial l
  if (h == 0) Lp[((size_t)bh << 11) + q0 + Lq] = l_part;
  #pragma unroll
  for (int r = 0; r < 16; ++r) {
    int qrow = (r & 3) + 8 * (r >> 2) + 4 * h;
    size_t rowb = ((size_t)b * 2048 + q0 + qrow) * 1024 + hh * 64;
    Pp[rowb + Lq]      = f2bf(o[0][r]);
    Pp[rowb + 32 + Lq] = f2bf(o[1][r]);
  }
  #undef STAGE_KV
}

// ------------------------------------- merge: AO = (P0+P1) / (l0+l1), bf16
__global__ void k_merge(const short* __restrict__ P0, const short* __restrict__ P1,
                        const float* __restrict__ L0, const float* __restrict__ L1,
                        short* __restrict__ AO)
{
  int idx = blockIdx.x * 256 + threadIdx.x;   // 8 elems each; 524288 threads
  int rg = idx >> 7;                 // row 0..4095 = b*2048 + l
  int c0 = (idx & 127) * 8;          // col base (within one 64-col head)
  int bh = ((rg >> 11) << 4) + (c0 >> 6);
  size_t lix = ((size_t)bh << 11) + (rg & 2047);
  float inv = 1.f / (L0[lix] + L1[lix]);
  size_t off = (size_t)rg * 1024 + c0;
  bf16x8 a = *reinterpret_cast<const bf16x8*>(&P0[off]);
  bf16x8 bv = *reinterpret_cast<const bf16x8*>(&P1[off]);
  bf16x8 r;
  #pragma unroll
  for (int j = 0; j < 8; ++j)
    r[j] = f2bf((bf2f(a[j]) + bf2f(bv[j])) * inv);
  *reinterpret_cast<bf16x8*>(&AO[off]) = r;
}

// ----------------------------------------------------------------------------
extern "C" void kernel_launch(void* const* d_in, const int* in_sizes, int n_in,
                              void* d_out, int out_size, void* d_ws, size_t ws_size,
                              hipStream_t stream) {
  (void)in_sizes; (void)n_in; (void)out_size; (void)ws_size;
  const float* x    = (const float*)d_in[0];
  const float* rc   = (const float*)d_in[1];
  const float* rs   = (const float*)d_in[2];
  const float* Wqkv = (const float*)d_in[3];
  const float* bqkv = (const float*)d_in[4];
  const float* Wout = (const float*)d_in[5];
  const float* bout = (const float*)d_in[6];
  float* out = (float*)d_out;

  char* ws = (char*)d_ws;
  short* xb  = (short*)(ws);              // x bf16        [4096][1024]  8.39MB
  short* wqb = (short*)(ws + 8388608);    // Wqkv bf16     [3072][1024]  6.29MB
  short* wob = (short*)(ws + 14680064);   // Wout bf16     [1024][1024]  2.10MB
  short* Qb  = (short*)(ws + 16777216);   // Q roped+scaled[32][2048][64] 8.39MB
  short* Kb  = (short*)(ws + 25165824);   // K roped       [32][2048][64] 8.39MB
  short* Vt  = (short*)(ws + 33554432);   // V transposed  [32][64][2048] 8.39MB
  short* P0  = (short*)(ws + 41943040);   // o partial z=0 [4096][1024]  8.39MB
  short* P1  = (short*)(ws + 50331648);   // o partial z=1 [4096][1024]  8.39MB
  float* L0  = (float*)(ws + 58720256);   // l partial z=0 [32][2048]    0.26MB
  float* L1  = (float*)(ws + 58982400);   // l partial z=1 [32][2048]    0.26MB
                                          // total 59.2MB

  k_cvt_all<<<8192, 256, 0, stream>>>(x, Wqkv, Wout, xb, wqb, wob);
  k_gemm_qkv<<<dim3(24, 32), 512, 0, stream>>>(xb, wqb, bqkv, rc, rs, Qb, Kb, Vt);
  k_attn<<<dim3(16, 32, 2), 256, 0, stream>>>(Qb, Kb, Vt, P0, P1, L0, L1);
  k_merge<<<2048, 256, 0, stream>>>(P0, P1, L0, L1, P0);
  k_gemm_out<<<dim3(8, 32), 512, 0, stream>>>(P0, wob, bout, out);
}

// Round 24
// 108.758 us; speedup vs baseline: 1.5026x; 1.0223x over previous
//
#include <hip/hip_runtime.h>
#include <hip/hip_bf16.h>
#include <stdint.h>

// RoPE self-attention, bf16-MFMA pipeline.  == R21 checkpoint (108.6us) ==
// B=2 L=2048 D=1024 H=16 DK=64. GEMM1 fuses bias+RoPE+pack (Q,K) and
// bias+transpose (V), LDS-vectorized epilogue. GEMMs: 2-slot prefetch,
// 8 waves of 32x64 per 128x128 tile (4 waves/SIMD), T2 XOR-swizzled LDS,
// 2-D XCD-chunked grid swizzle. NO loop unrolls anywhere (R22: attn
// unroll4 spilled accumulators, 2.2x; R23: gemm unroll2 cost ~2.5us).
// Attention: 32x32x16 MFMA, in-register P via cvt_pk+permlane32_swap,
// split-KV (z=2) additive partials + merge, phase-split inner loop
// (4 waves/SIMD). Single fused cvt launch. Q pre-scaled by 0.125*log2(e).

typedef __attribute__((ext_vector_type(8)))  short bf16x8;   // MFMA A/B frag
typedef __attribute__((ext_vector_type(4)))  float f32x4;    // 16x16 C/D frag
typedef __attribute__((ext_vector_type(16))) float f32x16;   // 32x32 C/D frag
typedef __attribute__((ext_vector_type(4)))  short short4v;
typedef __attribute__((ext_vector_type(4)))  unsigned int u32x4;

#define DEV static __device__ __forceinline__

DEV short f2bf(float f) {            // RNE f32->bf16
  uint32_t u = __builtin_bit_cast(uint32_t, f);
  u += 0x7FFFu + ((u >> 16) & 1u);
  return (short)(u >> 16);
}
DEV float bf2f(short s) {
  return __builtin_bit_cast(float, ((uint32_t)(uint16_t)s) << 16);
}
DEV uint32_t pkbf(float a, float b) { // packed f32x2 -> bf16x2 (v_cvt_pk path)
  __hip_bfloat162 h = __float22bfloat162_rn(make_float2(a, b));
  uint32_t u;
  __builtin_memcpy(&u, &h, 4);
  return u;
}
// v_permlane32_swap_b32 vdst, vsrc: dst.upper <-> src.lower (verified R7)
DEV void pl32swap(uint32_t &dst, uint32_t &src) {
  asm volatile("v_permlane32_swap_b32 %0, %1" : "+v"(dst), "+v"(src));
}

#define AS1 __attribute__((address_space(1)))
#define AS3 __attribute__((address_space(3)))
#define GLOAD_LDS16(gp, lp) \
  __builtin_amdgcn_global_load_lds((const AS1 void*)(gp), (AS3 void*)(lp), 16, 0, 0)

// ------------------------------------- f32 -> bf16, all three tensors fused
// blocks [0,4096): x (1048576 f4) | [4096,7168): Wqkv (786432) | rest: Wout.
__global__ void k_cvt_all(const float* __restrict__ x, const float* __restrict__ wq,
                          const float* __restrict__ wo,
                          short* __restrict__ xb, short* __restrict__ wqb,
                          short* __restrict__ wob) {
  int bid = blockIdx.x;
  const float* in;
  short* out;
  int i;
  if (bid < 4096)      { in = x;  out = xb;  i = bid * 256 + threadIdx.x; }
  else if (bid < 7168) { in = wq; out = wqb; i = (bid - 4096) * 256 + threadIdx.x; }
  else                 { in = wo; out = wob; i = (bid - 7168) * 256 + threadIdx.x; }
  float4 v = reinterpret_cast<const float4*>(in)[i];
  short4v o = { f2bf(v.x), f2bf(v.y), f2bf(v.z), f2bf(v.w) };
  reinterpret_cast<short4v*>(out)[i] = o;
}

// ---------------------------------------------- GEMM tile stage (128x64 x2)
// 512 threads: 2 chunks each of A and B. Source pre-swizzled (rule #21).
DEV void gemm_stage(const short* Ag, const short* Bg, int K_,
                    short* AsD, short* BsD, int tid) {
  #pragma unroll
  for (int p = 0; p < 2; ++p) {
    int f = p * 512 + tid;
    int row = f >> 3;
    int sch = (f & 7) ^ (row & 7);
    GLOAD_LDS16(Ag + (size_t)row * K_ + sch * 8, AsD + f * 8);
    GLOAD_LDS16(Bg + (size_t)row * K_ + sch * 8, BsD + f * 8);
  }
}

// -------------------------------------------------------------- GEMM template
// C128x128 = A[M][K] @ Bt[N][K]^T, BK=64, 8 waves (4 wr x 2 wc) of 32x64,
// 2-slot prefetch, T2 XOR swizzle. 2-D XCD chunking: XCD x owns an
// (gy/4 m) x (gx/2 n) tile rectangle (cm = x&3, cn = x>>2), row-major
// inside -> per-XCD L2 working set ~1 A-panel + gx/2 B-panels.
#define GEMM_BODY(A_, Bt_, K_)                                              \
  __shared__ short Lds[4 * 128 * 64];   /* 64KB: slot stride 16384 shorts */\
  const int tid = threadIdx.x;                                              \
  const int lane = tid & 63;                                                \
  const int wid  = tid >> 6;           /* 0..7 */                           \
  const int lq = lane & 15, lg = lane >> 4;                                 \
  const int wr = wid >> 1, wc = wid & 1;                                    \
  int lin_ = blockIdx.y * gridDim.x + blockIdx.x;                           \
  const int xcd_ = lin_ & 7;                                                \
  const int j_   = lin_ >> 3;                                               \
  const int hx_  = gridDim.x >> 1;     /* n tiles per chunk */              \
  const int hy_  = gridDim.y >> 2;     /* m tiles per chunk */              \
  const int m0 = ((xcd_ & 3) * hy_ + j_ / hx_) * 128;                       \
  const int n0 = ((xcd_ >> 2) * hx_ + j_ % hx_) * 128;                      \
  f32x4 acc[2][4];                                                          \
  _Pragma("unroll")                                                         \
  for (int i = 0; i < 2; ++i)                                               \
    _Pragma("unroll")                                                       \
    for (int j = 0; j < 4; ++j) acc[i][j] = (f32x4){0.f, 0.f, 0.f, 0.f};    \
  const int KT = (K_) >> 6;                                                 \
  gemm_stage((A_) + (size_t)m0 * (K_), (Bt_) + (size_t)n0 * (K_), (K_),     \
             Lds, Lds + 8192, tid);                                         \
  __syncthreads();                                                          \
  int gbuf = 0;                                                             \
  for (int kt = 0; kt < KT; ++kt) {                                         \
    if (kt + 1 < KT)                                                        \
      gemm_stage((A_)  + (size_t)m0 * (K_) + (kt + 1) * 64,                 \
                 (Bt_) + (size_t)n0 * (K_) + (kt + 1) * 64, (K_),           \
                 Lds + (gbuf ^ 1) * 16384,                                  \
                 Lds + (gbuf ^ 1) * 16384 + 8192, tid);                     \
    const short* As = Lds + gbuf * 16384;                                   \
    const short* Bs = As + 8192;                                            \
    _Pragma("unroll")                                                       \
    for (int kk = 0; kk < 2; ++kk) {                                        \
      bf16x8 af[2], bfr[4];                                                 \
      _Pragma("unroll")                                                     \
      for (int i = 0; i < 2; ++i)                                           \
        af[i]  = *reinterpret_cast<const bf16x8*>(                          \
            &As[(wr*32 + i*16 + lq) * 64 + (((kk*4 + lg) ^ (lq & 7)) * 8)]);\
      _Pragma("unroll")                                                     \
      for (int j = 0; j < 4; ++j)                                           \
        bfr[j] = *reinterpret_cast<const bf16x8*>(                          \
            &Bs[(wc*64 + j*16 + lq) * 64 + (((kk*4 + lg) ^ (lq & 7)) * 8)]);\
      _Pragma("unroll")                                                     \
      for (int i = 0; i < 2; ++i)                                           \
        _Pragma("unroll")                                                   \
        for (int j = 0; j < 4; ++j)                                         \
          acc[i][j] = __builtin_amdgcn_mfma_f32_16x16x32_bf16(              \
              af[i], bfr[j], acc[i][j], 0, 0, 0);                           \
    }                                                                       \
    __syncthreads();                                                        \
    gbuf ^= 1;                                                              \
  }

// ---------------- GEMM1: x @ Wqkv^T + b, fused RoPE(Q,K-scaled) + V-transpose
__global__ __launch_bounds__(512, 4) void k_gemm_qkv(
    const short* __restrict__ A, const short* __restrict__ Bt,
    const float* __restrict__ bias,
    const float* __restrict__ cosb, const float* __restrict__ sinb,
    short* __restrict__ Qb, short* __restrict__ Kb, short* __restrict__ Vt)
{
  GEMM_BODY(A, Bt, 1024)

  short* Ep = Lds + wid * 2048;                // per-wave 4KB scratch
  const int cglob = n0 + wc * 64;              // head base col in [0,3072)
  if (cglob < 2048) {                          // ---- Q or K: bias + RoPE
    const bool isq = (cglob < 1024);
    const float QS = isq ? 0.125f * 1.4426950408889634f : 1.0f;
    short* dst = isq ? Qb : Kb;
    const int h = (cglob & 1023) >> 6;
    const float b0 = bias[cglob + lq],      b2 = bias[cglob + 32 + lq];
    const float b1 = bias[cglob + 16 + lq], b3 = bias[cglob + 48 + lq];
    #pragma unroll
    for (int i = 0; i < 2; ++i) {
      #pragma unroll
      for (int r = 0; r < 4; ++r) {
        int lloc = i*16 + lg*4 + r;                // 0..31 within wave strip
        int rg = m0 + wr*32 + lloc;                // global row = b*2048 + l
        float c0 = cosb[(size_t)rg * 32 + lq];
        float s0 = sinb[(size_t)rg * 32 + lq];
        float c1 = cosb[(size_t)rg * 32 + 16 + lq];
        float s1 = sinb[(size_t)rg * 32 + 16 + lq];
        float x1 = acc[i][0][r] + b0, x2 = acc[i][2][r] + b2;   // d = lq
        Ep[lloc*64 + lq]      = f2bf((x1 * c0 - x2 * s0) * QS);
        Ep[lloc*64 + 32 + lq] = f2bf((x1 * s0 + x2 * c0) * QS);
        float y1 = acc[i][1][r] + b1, y2 = acc[i][3][r] + b3;   // d = 16+lq
        Ep[lloc*64 + 16 + lq] = f2bf((y1 * c1 - y2 * s1) * QS);
        Ep[lloc*64 + 48 + lq] = f2bf((y1 * s1 + y2 * c1) * QS);
      }
    }
    #pragma unroll
    for (int p = 0; p < 4; ++p) {              // 256 chunks / 64 lanes
      int f = p * 64 + lane;
      int lloc = f >> 3, d0 = (f & 7) * 8;
      int rg = m0 + wr*32 + lloc;
      int bi = rg >> 11, ll = rg & 2047;
      bf16x8 v = *reinterpret_cast<const bf16x8*>(&Ep[lloc*64 + d0]);
      *reinterpret_cast<bf16x8*>(
          &dst[((size_t)(bi * 16 + h) * 2048 + ll) * 64 + d0]) = v;
    }
  } else {                                     // ---- V: bias + transpose
    const int h = (cglob - 2048) >> 6;
    // d-major Ep[d][32 l], swizzle lloc ^= ((d>>1)&3)<<3 (8 16B slots/16
    // lanes = 2-way = free; 16B read-back stays contiguous)
    #pragma unroll
    for (int i = 0; i < 2; ++i) {
      int lloc = i*16 + lg*4;                      // 4 consecutive l
      #pragma unroll
      for (int j = 0; j < 4; ++j) {
        int d = j * 16 + lq;
        float bv = bias[cglob + d];
        short4v pk4 = { f2bf(acc[i][j][0] + bv), f2bf(acc[i][j][1] + bv),
                        f2bf(acc[i][j][2] + bv), f2bf(acc[i][j][3] + bv) };
        *reinterpret_cast<short4v*>(
            &Ep[d*32 + (lloc ^ (((d >> 1) & 3) << 3))]) = pk4;
      }
    }
    #pragma unroll
    for (int p = 0; p < 4; ++p) {              // 256 chunks: 64 d x 4 of 8l
      int f = p * 64 + lane;
      int d = f >> 2, lc = (f & 3) * 8;
      bf16x8 v = *reinterpret_cast<const bf16x8*>(&Ep[d*32 + lc]);
      int lreal = lc ^ (((d >> 1) & 3) << 3);
      int rg = m0 + wr*32 + lreal;                 // 8-aligned run of l
      int bi = rg >> 11, ll = rg & 2047;
      *reinterpret_cast<bf16x8*>(
          &Vt[((size_t)(bi * 16 + h) * 64 + d) * 2048 + ll]) = v;
    }
  }
}

// -------------------------------------------- GEMM2: AO @ Wout^T + b, f32 out
__global__ __launch_bounds__(512, 4) void k_gemm_out(
    const short* __restrict__ A, const short* __restrict__ Bt,
    const float* __restrict__ bias, float* __restrict__ C)
{
  GEMM_BODY(A, Bt, 1024)
  const int N = 1024;
  #pragma unroll
  for (int i = 0; i < 2; ++i) {
    int rbase = m0 + wr*32 + i*16 + lg*4;
    #pragma unroll
    for (int j = 0; j < 4; ++j) {
      int col = n0 + wc*64 + j*16 + lq;
      float bv = bias[col];
      #pragma unroll
      for (int r = 0; r < 4; ++r)
        C[(size_t)(rbase + r) * N + col] = acc[i][j][r] + bv;
    }
  }
}

// ------------------------------------------------------------ flash attention
// Split-KV: blockIdx.z selects kv-half (16 tiles of 64). 4 waves/block,
// 32 q-rows/wave (32x32x16 MFMA). K/V staged in LDS, 2-buffer. Phase-split
// inner loop keeps unified VGPR+AGPR < 128 -> 4 waves/SIMD. Natural blockIdx
// mapping; no setprio, no unroll (all measured null/negative R14-R22).
__global__ __launch_bounds__(256, 4) void k_attn(
    const short* __restrict__ Q, const short* __restrict__ Kb,
    const short* __restrict__ Vt,
    short* __restrict__ P0, short* __restrict__ P1,
    float* __restrict__ L0, float* __restrict__ L1)
{
  __shared__ short Ks[2][64 * 64];   // 8KB x2, swizzled, rows = kv
  __shared__ short Vs[2][64 * 64];   // 8KB x2, swizzled, rows = d
  const int tid = threadIdx.x;
  const int lane = tid & 63;
  const int wid  = tid >> 6;         // 0..3
  const int Lq = lane & 31;          // q-col / d-col / kv-row
  const int h  = lane >> 5;          // half-select
  const int bh = blockIdx.y;
  const int q0 = blockIdx.x * 128 + wid * 32;
  const int b = bh >> 4, hh = bh & 15;
  const int t0 = blockIdx.z * 16;    // kv-tile base for this half
  short* Pp = blockIdx.z ? P1 : P0;
  float* Lp = blockIdx.z ? L1 : L0;

  const short* Qp = Q  + ((size_t)bh * 2048 + q0 + Lq) * 64;
  const short* Kp = Kb + (size_t)bh * 2048 * 64;
  const short* Vp = Vt + (size_t)bh * 64 * 2048;

  #define STAGE_KV(c, t) do {                                              \
    const short* Kg_ = Kp + (size_t)(t) * 64 * 64;                         \
    const short* Vg_ = Vp + (size_t)(t) * 64;                              \
    _Pragma("unroll")                                                      \
    for (int p_ = 0; p_ < 2; ++p_) {                                       \
      int f_ = p_ * 256 + tid;                                             \
      int row_ = f_ >> 3;                                                  \
      int sch_ = (f_ & 7) ^ (row_ & 7);                                    \
      GLOAD_LDS16(Kg_ + row_ * 64 + sch_ * 8,            &Ks[c][f_ * 8]);  \
      GLOAD_LDS16(Vg_ + (size_t)row_ * 2048 + sch_ * 8,  &Vs[c][f_ * 8]);  \
    }                                                                      \
  } while (0)

  bf16x8 qf[4];
  #pragma unroll
  for (int ks = 0; ks < 4; ++ks)
    qf[ks] = *reinterpret_cast<const bf16x8*>(Qp + ks * 16 + h * 8);

  f32x16 o[2];
  #pragma unroll
  for (int nd = 0; nd < 2; ++nd)
    #pragma unroll
    for (int r = 0; r < 16; ++r) o[nd][r] = 0.f;
  float la0 = 0.f, la1 = 0.f;

  STAGE_KV(0, t0);
  asm volatile("s_waitcnt vmcnt(0)" ::: "memory");
  __syncthreads();

  for (int kk2 = 0; kk2 < 16; ++kk2) {
    const int cur = kk2 & 1;
    if (kk2 < 15) STAGE_KV(cur ^ 1, t0 + kk2 + 1);   // prefetch overlaps

    #pragma unroll
    for (int mb = 0; mb < 2; ++mb) {       // 32-kv half of the tile
      f32x16 sm;
      #pragma unroll
      for (int r = 0; r < 16; ++r) sm[r] = 0.f;
      #pragma unroll
      for (int ks = 0; ks < 4; ++ks) {
        bf16x8 kf = *reinterpret_cast<const bf16x8*>(
            &Ks[cur][(mb*32 + Lq) * 64 + (((ks*2 + h) ^ (Lq & 7)) * 8)]);
        sm = __builtin_amdgcn_mfma_f32_32x32x16_bf16(kf, qf[ks], sm, 0, 0, 0);
      }
      #pragma unroll
      for (int half = 0; half < 2; ++half) {
        float e0 = __builtin_amdgcn_exp2f(sm[8*half + 0]);
        float e1 = __builtin_amdgcn_exp2f(sm[8*half + 1]);
        float e2 = __builtin_amdgcn_exp2f(sm[8*half + 2]);
        float e3 = __builtin_amdgcn_exp2f(sm[8*half + 3]);
        float e4 = __builtin_amdgcn_exp2f(sm[8*half + 4]);
        float e5 = __builtin_amdgcn_exp2f(sm[8*half + 5]);
        float e6 = __builtin_amdgcn_exp2f(sm[8*half + 6]);
        float e7 = __builtin_amdgcn_exp2f(sm[8*half + 7]);
        la0 += (e0 + e1) + (e4 + e5);
        la1 += (e2 + e3) + (e6 + e7);
        uint32_t w0 = pkbf(e0, e1), w1 = pkbf(e2, e3);
        uint32_t w2 = pkbf(e4, e5), w3 = pkbf(e6, e7);
        pl32swap(w0, w2);
        pl32swap(w1, w3);
        u32x4 paw = { w0, w1, w2, w3 };
        bf16x8 pa = __builtin_bit_cast(bf16x8, paw);
        const int ksl = mb * 2 + half;     // kv-slot 0..3
        #pragma unroll
        for (int nd = 0; nd < 2; ++nd) {
          bf16x8 vf = *reinterpret_cast<const bf16x8*>(
              &Vs[cur][(nd*32 + Lq) * 64 + (((ksl*2 + h) ^ (Lq & 7)) * 8)]);
          o[nd] = __builtin_amdgcn_mfma_f32_32x32x16_bf16(pa, vf, o[nd], 0, 0, 0);
        }
      }
    }
    asm volatile("s_waitcnt vmcnt(0)" ::: "memory");
    __syncthreads();                 // next tile staged; buffers swap
  }

  // ---- epilogue: partial l + UNNORMALIZED o (merge kernel normalizes)
  float l_part = la0 + la1;
  l_part += __shfl_xor(l_part, 32, 64);      // both h now hold full partial l
  if (h == 0) Lp[((size_t)bh << 11) + q0 + Lq] = l_part;
  #pragma unroll
  for (int r = 0; r < 16; ++r) {
    int qrow = (r & 3) + 8 * (r >> 2) + 4 * h;
    size_t rowb = ((size_t)b * 2048 + q0 + qrow) * 1024 + hh * 64;
    Pp[rowb + Lq]      = f2bf(o[0][r]);
    Pp[rowb + 32 + Lq] = f2bf(o[1][r]);
  }
  #undef STAGE_KV
}

// ------------------------------------- merge: AO = (P0+P1) / (l0+l1), bf16
__global__ void k_merge(const short* __restrict__ P0, const short* __restrict__ P1,
                        const float* __restrict__ L0, const float* __restrict__ L1,
                        short* __restrict__ AO)
{
  int idx = blockIdx.x * 256 + threadIdx.x;   // 8 elems each; 524288 threads
  int rg = idx >> 7;                 // row 0..4095 = b*2048 + l
  int c0 = (idx & 127) * 8;          // col base (within one 64-col head)
  int bh = ((rg >> 11) << 4) + (c0 >> 6);
  size_t lix = ((size_t)bh << 11) + (rg & 2047);
  float inv = 1.f / (L0[lix] + L1[lix]);
  size_t off = (size_t)rg * 1024 + c0;
  bf16x8 a = *reinterpret_cast<const bf16x8*>(&P0[off]);
  bf16x8 bv = *reinterpret_cast<const bf16x8*>(&P1[off]);
  bf16x8 r;
  #pragma unroll
  for (int j = 0; j < 8; ++j)
    r[j] = f2bf((bf2f(a[j]) + bf2f(bv[j])) * inv);
  *reinterpret_cast<bf16x8*>(&AO[off]) = r;
}

// ----------------------------------------------------------------------------
extern "C" void kernel_launch(void* const* d_in, const int* in_sizes, int n_in,
                              void* d_out, int out_size, void* d_ws, size_t ws_size,
                              hipStream_t stream) {
  (void)in_sizes; (void)n_in; (void)out_size; (void)ws_size;
  const float* x    = (const float*)d_in[0];
  const float* rc   = (const float*)d_in[1];
  const float* rs   = (const float*)d_in[2];
  const float* Wqkv = (const float*)d_in[3];
  const float* bqkv = (const float*)d_in[4];
  const float* Wout = (const float*)d_in[5];
  const float* bout = (const float*)d_in[6];
  float* out = (float*)d_out;

  char* ws = (char*)d_ws;
  short* xb  = (short*)(ws);              // x bf16        [4096][1024]  8.39MB
  short* wqb = (short*)(ws + 8388608);    // Wqkv bf16     [3072][1024]  6.29MB
  short* wob = (short*)(ws + 14680064);   // Wout bf16     [1024][1024]  2.10MB
  short* Qb  = (short*)(ws + 16777216);   // Q roped+scaled[32][2048][64] 8.39MB
  short* Kb  = (short*)(ws + 25165824);   // K roped       [32][2048][64] 8.39MB
  short* Vt  = (short*)(ws + 33554432);   // V transposed  [32][64][2048] 8.39MB
  short* P0  = (short*)(ws + 41943040);   // o partial z=0 [4096][1024]  8.39MB
  short* P1  = (short*)(ws + 50331648);   // o partial z=1 [4096][1024]  8.39MB
  float* L0  = (float*)(ws + 58720256);   // l partial z=0 [32][2048]    0.26MB
  float* L1  = (float*)(ws + 58982400);   // l partial z=1 [32][2048]    0.26MB
                                          // total 59.2MB

  k_cvt_all<<<8192, 256, 0, stream>>>(x, Wqkv, Wout, xb, wqb, wob);
  k_gemm_qkv<<<dim3(24, 32), 512, 0, stream>>>(xb, wqb, bqkv, rc, rs, Qb, Kb, Vt);
  k_attn<<<dim3(16, 32, 2), 256, 0, stream>>>(Qb, Kb, Vt, P0, P1, L0, L1);
  k_merge<<<2048, 256, 0, stream>>>(P0, P1, L0, L1, P0);
  k_gemm_out<<<dim3(8, 32), 512, 0, stream>>>(P0, wob, bout, out);
}